// Round 1
// baseline (1155.951 us; speedup 1.0000x reference)
//
#include <hip/hip_runtime.h>

#define H_DIM 256

// ---------------------------------------------------------------------------
// Phase 1: scatter. One block (256 threads) per triple; thread c handles
// column c. Loads of the 3 gathered rows are coalesced (256B/wave segments),
// atomics are contiguous per wave. rel row is loaded once, used twice.
// ---------------------------------------------------------------------------
__global__ __launch_bounds__(256) void scatter_kernel(
    const float* __restrict__ ns, const float* __restrict__ rs,
    const int* __restrict__ trip, float* __restrict__ agg, int n_trip)
{
    int t = blockIdx.x;
    if (t >= n_trip) return;
    int c = threadIdx.x;
    int s = trip[t * 3 + 0];
    int r = trip[t * 3 + 1];
    int o = trip[t * 3 + 2];
    float rel   = rs[(size_t)r * H_DIM + c];
    float m_s2o = ns[(size_t)s * H_DIM + c] + rel;   // -> agg[o]
    float m_o2s = ns[(size_t)o * H_DIM + c] + rel;   // -> agg[s]
    unsafeAtomicAdd(agg + (size_t)o * H_DIM + c, m_s2o);
    unsafeAtomicAdd(agg + (size_t)s * H_DIM + c, m_o2s);
}

// ---------------------------------------------------------------------------
// Phase 2: fused GEMM + bias + SiLU + residual.
//   out = ns + silu([ns | agg] @ W + b)
// Tile: BM=64 rows x BN=256 (full row) x BK=16. 256 threads, each computes
// 4 rows x 16 cols. agg aliases out: with BN=256 each block owns its rows
// exclusively (reads all agg cols of its rows before writing them).
// ---------------------------------------------------------------------------
__global__ __launch_bounds__(256) void gemm_kernel(
    const float* __restrict__ ns, const float* __restrict__ agg,
    const float* __restrict__ Wm, const float* __restrict__ bias,
    float* __restrict__ out, int M)
{
    __shared__ float As[16][68];    // [k][m], pad 64->68 keeps f4 reads aligned
    __shared__ float Bs[16][256];   // [k][n]

    const int tid  = threadIdx.x;
    const int ty   = tid >> 4;      // 0..15 -> row group (4 rows each)
    const int tx   = tid & 15;      // 0..15 -> col group (16 cols each)
    const int arow = tid >> 2;      // 0..63  A staging: row in tile
    const int aq   = tid & 3;       // 0..3   A staging: k-quad
    const int bk   = tid >> 4;      // 0..15  B staging: k in tile
    const int bq   = tid & 15;      // 0..15  B staging: col quad base
    const int rowBase = blockIdx.x * 64;

    float acc[4][16];
#pragma unroll
    for (int i = 0; i < 4; ++i)
#pragma unroll
        for (int j = 0; j < 16; ++j) acc[i][j] = 0.f;

    int gr = rowBase + arow;
    if (gr >= M) gr = M - 1;                 // clamp; stores are predicated
    const size_t arow_off = (size_t)gr * H_DIM;

    for (int kt = 0; kt < 32; ++kt) {
        // -------- global loads (A: concat[ns,agg] row chunk; B: W rows) ----
        const int kg = kt * 16 + aq * 4;     // global k for this thread's f4
        float4 av = (kg < 256)
            ? *(const float4*)(ns  + arow_off + kg)
            : *(const float4*)(agg + arow_off + (kg - 256));
        float4 bv[4];
        const int wrow = kt * 16 + bk;
#pragma unroll
        for (int rep = 0; rep < 4; ++rep)
            bv[rep] = *(const float4*)(Wm + (size_t)wrow * H_DIM + (bq + rep * 16) * 4);

        __syncthreads();
        // -------- LDS stores (A transposed to [k][m]) ----------------------
        As[aq * 4 + 0][arow] = av.x;
        As[aq * 4 + 1][arow] = av.y;
        As[aq * 4 + 2][arow] = av.z;
        As[aq * 4 + 3][arow] = av.w;
#pragma unroll
        for (int rep = 0; rep < 4; ++rep)
            *(float4*)&Bs[bk][(bq + rep * 16) * 4] = bv[rep];
        __syncthreads();

        // -------- compute: 16 k-steps x 64 FMA ----------------------------
#pragma unroll
        for (int k = 0; k < 16; ++k) {
            float4 a4 = *(const float4*)&As[k][ty * 4];
            float a[4] = {a4.x, a4.y, a4.z, a4.w};
            float4 b0 = *(const float4*)&Bs[k][tx * 16 + 0];
            float4 b1 = *(const float4*)&Bs[k][tx * 16 + 4];
            float4 b2 = *(const float4*)&Bs[k][tx * 16 + 8];
            float4 b3 = *(const float4*)&Bs[k][tx * 16 + 12];
            float b[16] = {b0.x, b0.y, b0.z, b0.w,
                           b1.x, b1.y, b1.z, b1.w,
                           b2.x, b2.y, b2.z, b2.w,
                           b3.x, b3.y, b3.z, b3.w};
#pragma unroll
            for (int i = 0; i < 4; ++i)
#pragma unroll
                for (int j = 0; j < 16; ++j)
                    acc[i][j] += a[i] * b[j];
        }
    }

    // -------- epilogue: bias + SiLU + residual, f4 stores ------------------
#pragma unroll
    for (int i = 0; i < 4; ++i) {
        int row = rowBase + ty * 4 + i;
        if (row < M) {
            size_t roff = (size_t)row * H_DIM;
#pragma unroll
            for (int rep = 0; rep < 4; ++rep) {
                int col = tx * 16 + rep * 4;
                float4 bb = *(const float4*)(bias + col);
                float4 nv = *(const float4*)(ns + roff + col);
                float4 ov;
                float x;
                x = acc[i][rep * 4 + 0] + bb.x; ov.x = nv.x + x / (1.f + __expf(-x));
                x = acc[i][rep * 4 + 1] + bb.y; ov.y = nv.y + x / (1.f + __expf(-x));
                x = acc[i][rep * 4 + 2] + bb.z; ov.z = nv.z + x / (1.f + __expf(-x));
                x = acc[i][rep * 4 + 3] + bb.w; ov.w = nv.w + x / (1.f + __expf(-x));
                *(float4*)(out + roff + col) = ov;
            }
        }
    }
}

extern "C" void kernel_launch(void* const* d_in, const int* in_sizes, int n_in,
                              void* d_out, int out_size, void* d_ws, size_t ws_size,
                              hipStream_t stream)
{
    const float* ns   = (const float*)d_in[0];
    const float* rs   = (const float*)d_in[1];
    const int*   tp   = (const int*)d_in[2];
    const float* Wm   = (const float*)d_in[3];
    const float* bias = (const float*)d_in[4];
    const int M      = in_sizes[0] / H_DIM;   // 100000 nodes
    const int n_trip = in_sizes[2] / 3;       // 300000 triples
    float* out = (float*)d_out;

    // agg lives in d_out (same size); zero it, scatter into it, then the
    // GEMM reads it and overwrites with the final output (row-exclusive).
    hipMemsetAsync(out, 0, (size_t)M * H_DIM * sizeof(float), stream);
    scatter_kernel<<<dim3(n_trip), dim3(256), 0, stream>>>(ns, rs, tp, out, n_trip);
    const int mb = (M + 63) / 64;
    gemm_kernel<<<dim3(mb), dim3(256), 0, stream>>>(ns, out, Wm, bias, out, M);
}

// Round 2
// 548.979 us; speedup vs baseline: 2.1056x; 2.1056x over previous
//
#include <hip/hip_runtime.h>

#define H 256
typedef unsigned int  uint;
typedef unsigned short ushort;
typedef float  floatx4 __attribute__((ext_vector_type(4)));
typedef short  shortx8 __attribute__((ext_vector_type(8)));

// ---- helpers ---------------------------------------------------------------
__device__ __forceinline__ ushort bf16rn(float f) {      // RNE f32->bf16
    uint u = __float_as_uint(f);
    u += 0x7FFF + ((u >> 16) & 1);
    return (ushort)(u >> 16);
}
__device__ __forceinline__ uint pkbf2(float a, float b) {
    return (uint)bf16rn(a) | ((uint)bf16rn(b) << 16);
}
// packed bf16x2 atomic add (global_atomic_pk_add_bf16, gfx940+) via asm —
// immune to builtin availability churn across ROCm versions.
__device__ __forceinline__ void atomic_pk_bf16(void* addr, uint v) {
    asm volatile("global_atomic_pk_add_bf16 %0, %1, off" :: "v"(addr), "v"(v) : "memory");
}
// async global->LDS, 16B per lane. LDS dst = wave-uniform base + lane*16.
__device__ __forceinline__ void glds16(const void* g, void* l) {
    __builtin_amdgcn_global_load_lds(
        (__attribute__((address_space(1))) void*)(unsigned long long)(g),
        (__attribute__((address_space(3))) void*)(l), 16, 0, 0);
}

// ---------------------------------------------------------------------------
// W (512x256 f32, k-major) -> Wt (256x512 bf16, n-major) into d_ws (256KB)
// ---------------------------------------------------------------------------
__global__ __launch_bounds__(256) void wt_kernel(const float* __restrict__ W,
                                                 ushort* __restrict__ Wt) {
    int k = blockIdx.x;          // 0..511
    int n = threadIdx.x;         // 0..255
    Wt[(size_t)n * 512 + k] = bf16rn(W[(size_t)k * H + n]);
}

// ---------------------------------------------------------------------------
// Scatter: 2 triples per 256-thread block; thread handles a column PAIR.
// agg accumulated as bf16 packed into the FIRST 512B of each d_out row
// (bytes [1024r, 1024r+512) — strictly inside out row r, keeps the GEMM's
// row-exclusive aliasing argument intact).
// ---------------------------------------------------------------------------
__global__ __launch_bounds__(256) void scatter_kernel(
    const float* __restrict__ ns, const float* __restrict__ rs,
    const int* __restrict__ trip, char* __restrict__ outbase, int n_trip)
{
    int t = blockIdx.x * 2 + (threadIdx.x >> 7);
    if (t >= n_trip) return;
    int p = threadIdx.x & 127;                       // column pair 0..127
    int s = trip[3 * t + 0];
    int r = trip[3 * t + 1];
    int o = trip[3 * t + 2];
    float2 vs = ((const float2*)ns)[(size_t)s * 128 + p];
    float2 vo = ((const float2*)ns)[(size_t)o * 128 + p];
    float2 vr = ((const float2*)rs)[(size_t)r * 128 + p];
    uint m_s2o = pkbf2(vs.x + vr.x, vs.y + vr.y);    // -> agg[o]
    uint m_o2s = pkbf2(vo.x + vr.x, vo.y + vr.y);    // -> agg[s]
    atomic_pk_bf16(outbase + (size_t)o * 1024 + p * 4, m_s2o);
    atomic_pk_bf16(outbase + (size_t)s * 1024 + p * 4, m_o2s);
}

// ---------------------------------------------------------------------------
// MFMA GEMM: out = ns + silu([ns|agg] @ W + b)
// Tile BM=64 x BN=256 x BK=32; 4 waves; wave w owns cols [64w,64w+64) as a
// 4x4 grid of 16x16x32 bf16 MFMA frags. K 0..255 = ns (fp32, convert in
// staging, padded LDS stride 40); K 256..511 = agg (bf16 in d_out row heads,
// global_load_lds). W via Wt (bf16 n-major), global_load_lds, stride-32 LDS.
// ---------------------------------------------------------------------------
__global__ __launch_bounds__(256) void gemm_kernel(
    const float* __restrict__ ns, const float* __restrict__ aggf,
    const ushort* __restrict__ Wt, const float* __restrict__ bias,
    float* __restrict__ out, int M)
{
    __shared__ __align__(16) ushort AsP[64 * 40];   // ns-half,  pad 32->40
    __shared__ __align__(16) ushort AsU[64 * 32];   // agg-half, unpadded
    __shared__ __align__(16) ushort Bs [256 * 32];  // Wt tile [n][k]

    const int tid  = threadIdx.x;
    const int wave = tid >> 6;
    const int lane = tid & 63;
    const int fm = lane & 15, fq = lane >> 4;       // frag row / quad
    const int rowBase = blockIdx.x * 64;

    floatx4 acc[4][4] = {};                          // [mi][ni]

    // staging maps: thread t -> tile row t>>2, k-quad t&3 (8 elems = 16B bf16)
    const int am = tid >> 2, akq = tid & 3;
    int arow = rowBase + am; if (arow >= M) arow = M - 1;
    const float* aptrA = ns + (size_t)arow * H + akq * 8;
    const char*  aggp  = (const char*)aggf + (size_t)arow * 1024 + akq * 16;
    const char*  wtp   = (const char*)Wt;

    // ---------------- phase A: kt 0..7 (A = ns, fp32 -> bf16) --------------
#pragma unroll
    for (int kt = 0; kt < 8; ++kt) {
        __syncthreads();
        float4 v0 = *(const float4*)(aptrA + kt * 32);
        float4 v1 = *(const float4*)(aptrA + kt * 32 + 4);
#pragma unroll
        for (int j = 0; j < 4; ++j)
            glds16(wtp + (size_t)(j * 64 + am) * 1024 + kt * 64 + akq * 16,
                   &Bs[j * 2048 + tid * 8]);
        uint4 pk;
        pk.x = pkbf2(v0.x, v0.y); pk.y = pkbf2(v0.z, v0.w);
        pk.z = pkbf2(v1.x, v1.y); pk.w = pkbf2(v1.z, v1.w);
        *(uint4*)&AsP[am * 40 + akq * 8] = pk;
        __syncthreads();

        shortx8 aF[4], bF[4];
#pragma unroll
        for (int mi = 0; mi < 4; ++mi)
            aF[mi] = *(const shortx8*)&AsP[(mi * 16 + fm) * 40 + fq * 8];
#pragma unroll
        for (int ni = 0; ni < 4; ++ni)
            bF[ni] = *(const shortx8*)&Bs[(wave * 64 + ni * 16 + fm) * 32 + fq * 8];
#pragma unroll
        for (int mi = 0; mi < 4; ++mi)
#pragma unroll
            for (int ni = 0; ni < 4; ++ni)
                acc[mi][ni] = __builtin_amdgcn_mfma_f32_16x16x32_bf16(
                    aF[mi], bF[ni], acc[mi][ni], 0, 0, 0);
    }

    // ---------------- phase B: kt 8..15 (A = agg bf16 via glds) ------------
#pragma unroll
    for (int kt = 0; kt < 8; ++kt) {
        __syncthreads();
        glds16(aggp + kt * 64, &AsU[tid * 8]);
#pragma unroll
        for (int j = 0; j < 4; ++j)
            glds16(wtp + (size_t)(j * 64 + am) * 1024 + (kt + 8) * 64 + akq * 16,
                   &Bs[j * 2048 + tid * 8]);
        __syncthreads();

        shortx8 aF[4], bF[4];
#pragma unroll
        for (int mi = 0; mi < 4; ++mi)
            aF[mi] = *(const shortx8*)&AsU[(mi * 16 + fm) * 32 + fq * 8];
#pragma unroll
        for (int ni = 0; ni < 4; ++ni)
            bF[ni] = *(const shortx8*)&Bs[(wave * 64 + ni * 16 + fm) * 32 + fq * 8];
#pragma unroll
        for (int mi = 0; mi < 4; ++mi)
#pragma unroll
            for (int ni = 0; ni < 4; ++ni)
                acc[mi][ni] = __builtin_amdgcn_mfma_f32_16x16x32_bf16(
                    aF[mi], bF[ni], acc[mi][ni], 0, 0, 0);
    }

    // ---------------- epilogue: bias + SiLU + residual ---------------------
    // C/D layout: col = lane&15, row = (lane>>4)*4 + reg  [m89/m91 verified]
#pragma unroll
    for (int mi = 0; mi < 4; ++mi) {
#pragma unroll
        for (int ni = 0; ni < 4; ++ni) {
            int col = wave * 64 + ni * 16 + fm;
            float bc = bias[col];
#pragma unroll
            for (int r = 0; r < 4; ++r) {
                int row = rowBase + mi * 16 + fq * 4 + r;
                if (row < M) {
                    float x = acc[mi][ni][r] + bc;
                    float sg = 1.f / (1.f + __expf(-x));
                    out[(size_t)row * H + col] = ns[(size_t)row * H + col] + x * sg;
                }
            }
        }
    }
}

extern "C" void kernel_launch(void* const* d_in, const int* in_sizes, int n_in,
                              void* d_out, int out_size, void* d_ws, size_t ws_size,
                              hipStream_t stream)
{
    const float* ns   = (const float*)d_in[0];
    const float* rs   = (const float*)d_in[1];
    const int*   tp   = (const int*)d_in[2];
    const float* Wm   = (const float*)d_in[3];
    const float* bias = (const float*)d_in[4];
    const int M      = in_sizes[0] / H;      // 100000
    const int n_trip = in_sizes[2] / 3;      // 300000
    float*  out = (float*)d_out;
    ushort* Wt  = (ushort*)d_ws;             // 256KB

    hipMemsetAsync(d_out, 0, (size_t)M * H * sizeof(float), stream);
    wt_kernel<<<dim3(512), dim3(256), 0, stream>>>(Wm, Wt);
    scatter_kernel<<<dim3((n_trip + 1) / 2), dim3(256), 0, stream>>>(
        ns, rs, tp, (char*)d_out, n_trip);
    gemm_kernel<<<dim3((M + 63) / 64), dim3(256), 0, stream>>>(
        ns, out, Wt, bias, out, M);
}